// Round 17
// baseline (254.525 us; speedup 1.0000x reference)
//
#include <hip/hip_runtime.h>
#include <hip/hip_bf16.h>
#include <math.h>

#define NNODES 4096
#define NHEADS 4
#define MAXDEG 128

typedef __attribute__((ext_vector_type(8))) short  bf16x8;
typedef __attribute__((ext_vector_type(4))) float  f32x4;
typedef __attribute__((ext_vector_type(4))) unsigned short us4;

__device__ __forceinline__ unsigned short f2bf(float v) {
    unsigned int x = __float_as_uint(v);
    unsigned int r = (x + 0x7fffu + ((x >> 16) & 1u)) >> 16;   // RNE
    return (unsigned short)r;
}

// float -> fp8 e4m3fn (OCP), RNE. Software encode (cold path) consistent with
// gfx950's hardware OCP decode.
__device__ __forceinline__ unsigned char f2f8(float v) {
    unsigned int u = __float_as_uint(v);
    unsigned int s = (u >> 24) & 0x80u;
    u &= 0x7fffffffu;
    int e = (int)(u >> 23) - 127;
    if (e < -6) {                                   // fp8-subnormal: step 2^-9
        float q = __uint_as_float(u) * 512.f;
        int m = (int)rintf(q);
        if (m <= 0) return (unsigned char)s;
        if (m >= 8) return (unsigned char)(s | 0x08);
        return (unsigned char)(s | m);
    }
    unsigned int rr = (u + 0x7ffffu + ((u >> 20) & 1u)) >> 20;  // [exp8|man3]
    int e2 = (int)(rr >> 3) - 127;
    unsigned int m3 = rr & 7u;
    if (e2 > 8 || (e2 == 8 && m3 == 7u)) return (unsigned char)(s | 0x7e);  // clamp 448
    return (unsigned char)(s | (unsigned int)((e2 + 7) << 3) | m3);
}

__device__ __forceinline__ void gload_lds16(const unsigned short* g, unsigned short* l) {
    __builtin_amdgcn_global_load_lds(
        (const __attribute__((address_space(1))) unsigned int*)(g),
        (__attribute__((address_space(3))) unsigned int*)(l), 16, 0, 0);
}

// ---------------- fused preamble: csr | cvt | transposes, by blockIdx range ----------
__global__ __launch_bounds__(256) void preamble(
    const int* __restrict__ er, const int* __restrict__ ec,
    unsigned int* __restrict__ bitmap, int* __restrict__ cnt, int* __restrict__ cols, int E,
    const float* __restrict__ x, unsigned short* __restrict__ xb,
    const float* __restrict__ W1, unsigned short* __restrict__ Wt1,
    const float* __restrict__ pW, unsigned short* __restrict__ pWt,
    const float* __restrict__ Wk, unsigned short* __restrict__ Wtk)
{
    __shared__ float tile[32][33];
    int b = blockIdx.x;
    int tid = threadIdx.x;
    if (b < 512) {                                   // ---- CSR with bitmap dedupe
        int e = b * 256 + tid;
        if (e >= E) return;
        int r = er[e], c = ec[e];
        unsigned int idx = ((unsigned int)r << 12) | (unsigned int)c;
        unsigned int bit = 1u << (idx & 31);
        unsigned int old = atomicOr(&bitmap[idx >> 5], bit);
        if (!(old & bit)) {
            int slot = atomicAdd(&cnt[r], 1);
            if (slot < MAXDEG) cols[r * MAXDEG + slot] = c;
        }
    } else if (b < 2560) {                           // ---- fp32 -> bf16 (x)
        int i = (b - 512) * 256 + tid;
        float4 v = *(const float4*)(x + (size_t)i * 4);
        us4 o; o.x = f2bf(v.x); o.y = f2bf(v.y); o.z = f2bf(v.z); o.w = f2bf(v.w);
        *(us4*)(xb + (size_t)i * 4) = o;
    } else if (b < 3200) {                           // ---- K=512 transpose (W1 heads + pW)
        int idx = b - 2560;
        int k0 = (idx & 15) * 32;
        int j0 = ((idx >> 4) & 7) * 32;
        int z  = idx >> 7;                           // 0..4
        const float* W = (z < 4) ? W1 + (size_t)z * 512 * 256 : pW;
        unsigned short* Wt = (z < 4) ? Wt1 + (size_t)z * 256 * 512 : pWt;
        int tj = tid & 31, tk = tid >> 5;
#pragma unroll
        for (int it = 0; it < 4; ++it) {
            int kl = tk + it * 8;
            tile[kl][tj] = W[(size_t)(k0 + kl) * 256 + j0 + tj];
        }
        __syncthreads();
#pragma unroll
        for (int it = 0; it < 4; ++it) {
            int jl = tk + it * 8;
            Wt[(size_t)(j0 + jl) * 512 + k0 + tj] = f2bf(tile[tj][jl]);
        }
    } else {                                         // ---- K=256 transpose (Wk, 12 mats)
        int idx = b - 3200;
        int k0 = (idx & 7) * 32;
        int j0 = ((idx >> 3) & 7) * 32;
        int z  = idx >> 6;                           // 0..11
        const float* W = Wk + (size_t)z * 256 * 256;
        unsigned short* Wt = Wtk + (size_t)z * 256 * 256;
        int tj = tid & 31, tk = tid >> 5;
#pragma unroll
        for (int it = 0; it < 4; ++it) {
            int kl = tk + it * 8;
            tile[kl][tj] = W[(size_t)(k0 + kl) * 256 + j0 + tj];
        }
        __syncthreads();
#pragma unroll
        for (int it = 0; it < 4; ++it) {
            int jl = tk + it * 8;
            Wt[(size_t)(j0 + jl) * 256 + k0 + tj] = f2bf(tile[tj][jl]);
        }
    }
}

// ---------------- bf16 MFMA GEMM, 64x64 tile, BK=128, XCD-swizzled (R14 champion) ------
// wh1/wh2 epilogue atomics target [node][4] layout (float4-gatherable in attn).
template <int HASPROJ>
__global__ __launch_bounds__(256) void gemm_mfma(
    const unsigned short* __restrict__ A, const unsigned short* __restrict__ Bt,
    const unsigned short* __restrict__ pBt, const float* __restrict__ pb,
    float* __restrict__ Cproj, unsigned char* __restrict__ Cf8,
    const float* __restrict__ av, float* __restrict__ wh1, float* __restrict__ wh2,
    float* __restrict__ colsum, int K)
{
    __shared__ unsigned short As[64 * 128];   // 64 rows x 256B = 16KB
    __shared__ unsigned short Bs[64 * 128];
    int tid = threadIdx.x;
    int lane = tid & 63;
    int wave = tid >> 6;
    int wr = wave >> 1, wc = wave & 1;

    // XCD-aware swizzle (bijective: gridDim.x % 8 == 0)
    const int WB = HASPROJ ? 20 : 16;         // bn count
    int nwg = gridDim.x;
    int orig = blockIdx.x;
    int swz = (orig & 7) * (nwg >> 3) + (orig >> 3);
    int bn = swz % WB;
    int bm = swz / WB;

    int tileM = bm * 64;
    bool isProj = HASPROJ && (bn >= 16);
    const unsigned short* B = isProj ? pBt + (size_t)(bn - 16) * 64 * K
                                     : Bt + (size_t)bn * 64 * K;

    f32x4 acc[2][2];
#pragma unroll
    for (int m = 0; m < 2; ++m)
#pragma unroll
        for (int n = 0; n < 2; ++n) acc[m][n] = (f32x4){0.f, 0.f, 0.f, 0.f};

    int rowr  = tid >> 4;                    // 0..15
    int gslot = (tid & 15) ^ (rowr & 7);
    const unsigned short* gA = A + (size_t)(tileM + rowr) * K + gslot * 8;
    const unsigned short* gB = B + (size_t)rowr * K + gslot * 8;
    unsigned short* lA = As + tid * 8;
    unsigned short* lB = Bs + tid * 8;

    int fr = lane & 15;
    int kq = lane >> 4;
    int nsteps = K >> 7;

    int arow[2], brow[2];
#pragma unroll
    for (int m = 0; m < 2; ++m) arow[m] = wr * 32 + m * 16 + fr;
#pragma unroll
    for (int n = 0; n < 2; ++n) brow[n] = wc * 32 + n * 16 + fr;

    for (int t = 0; t < nsteps; ++t) {
#pragma unroll
        for (int r = 0; r < 4; ++r) {
            gload_lds16(gA + (size_t)r * 16 * K, lA + r * 2048);
            gload_lds16(gB + (size_t)r * 16 * K, lB + r * 2048);
        }
        gA += 128; gB += 128;
        __syncthreads();
#pragma unroll
        for (int ks = 0; ks < 4; ++ks) {
            bf16x8 af[2], bfv[2];
#pragma unroll
            for (int m = 0; m < 2; ++m) {
                int sl = ((ks * 4 + kq) ^ (arow[m] & 7)) * 8;
                af[m] = *(const bf16x8*)(As + arow[m] * 128 + sl);
            }
#pragma unroll
            for (int n = 0; n < 2; ++n) {
                int sl = ((ks * 4 + kq) ^ (brow[n] & 7)) * 8;
                bfv[n] = *(const bf16x8*)(Bs + brow[n] * 128 + sl);
            }
#pragma unroll
            for (int m = 0; m < 2; ++m)
#pragma unroll
                for (int n = 0; n < 2; ++n)
                    acc[m][n] = __builtin_amdgcn_mfma_f32_16x16x32_bf16(
                        af[m], bfv[n], acc[m][n], 0, 0, 0);
        }
        if (t + 1 < nsteps) __syncthreads();
    }

    int crow0 = tileM + wr * 32;

    if (!isProj) {
        int ccol0 = bn * 64 + wc * 32;
        int head = bn >> 2;
#pragma unroll
        for (int n = 0; n < 2; ++n) {
            float s = 0.f;
#pragma unroll
            for (int m = 0; m < 2; ++m)
#pragma unroll
                for (int q = 0; q < 4; ++q) s += acc[m][n][q];
            s += __shfl_xor(s, 16);
            s += __shfl_xor(s, 32);
            if (kq == 0)
                atomicAdd(colsum + ccol0 + n * 16 + fr, s);
        }
        float c1[2], c2[2];
#pragma unroll
        for (int n = 0; n < 2; ++n) {
            int j = (ccol0 + n * 16 + fr) & 255;
            c1[n] = av[head * 512 + j];
            c2[n] = av[head * 512 + 256 + j];
        }
#pragma unroll
        for (int m = 0; m < 2; ++m)
#pragma unroll
            for (int q = 0; q < 4; ++q) {
                float p1 = 0.f, p2 = 0.f;
#pragma unroll
                for (int n = 0; n < 2; ++n) {
                    p1 += acc[m][n][q] * c1[n];
                    p2 += acc[m][n][q] * c2[n];
                }
#pragma unroll
                for (int o = 1; o < 16; o <<= 1) {
                    p1 += __shfl_xor(p1, o);
                    p2 += __shfl_xor(p2, o);
                }
                if (fr == 0) {
                    int r = crow0 + m * 16 + kq * 4 + q;
                    atomicAdd(wh1 + r * 4 + head, p1);    // [node][4] layout
                    atomicAdd(wh2 + r * 4 + head, p2);
                }
            }
        // fp8 C store, node-major (row stride 1024 bytes)
#pragma unroll
        for (int m = 0; m < 2; ++m)
#pragma unroll
            for (int n = 0; n < 2; ++n) {
                int r0 = crow0 + m * 16 + kq * 4;
                int c  = ccol0 + n * 16 + fr;
#pragma unroll
                for (int q = 0; q < 4; ++q)
                    Cf8[(size_t)(r0 + q) * 1024 + c] = f2f8(acc[m][n][q]);
            }
    } else {
        int pcol0 = (bn - 16) * 64 + wc * 32;
#pragma unroll
        for (int m = 0; m < 2; ++m)
#pragma unroll
            for (int n = 0; n < 2; ++n) {
                int r0 = crow0 + m * 16 + kq * 4;
                int c  = pcol0 + n * 16 + fr;
                float bv = pb[c & 255];
#pragma unroll
                for (int q = 0; q < 4; ++q)
                    Cproj[(size_t)(r0 + q) * 256 + c] = acc[m][n][q] + bv;
            }
    }
}

// ---------------- per-row attention: 4 rows/block, wave/row, fp8 uint4 gather ------
// lane = h*16 + f. float4 wh gather; head-mean via shfl_xor(16/32); no fsum LDS.
__global__ __launch_bounds__(256) void row_attn(
    const unsigned char* __restrict__ h_f8, const float* __restrict__ wh1,
    const float* __restrict__ wh2, const float* __restrict__ colsum,
    const int* __restrict__ cnt, const int* __restrict__ cols,
    const float* __restrict__ bias, const float* __restrict__ prev,
    float* __restrict__ outp, unsigned short* __restrict__ out_bf, int N)
{
    int t = threadIdx.x;
    int rr = t >> 6;               // row-in-block 0..3
    int lane = t & 63;
    int h = lane >> 4;             // head
    int f = lane & 15;             // 16-feature slice
    int i = blockIdx.x * 4 + rr;
    __shared__ int   colsS[4][MAXDEG];
    __shared__ float wSt[4][4][MAXDEG];
    int deg = cnt[i];
    if (deg > MAXDEG) deg = MAXDEG;

    float4 w1 = *(const float4*)(wh1 + i * 4);
    for (int k = lane; k < deg; k += 64) {
        int c = cols[i * MAXDEG + k];
        colsS[rr][k] = c;
        float4 w2 = *(const float4*)(wh2 + c * 4);
        float s0 = w1.x + w2.x, s1 = w1.y + w2.y;
        float s2 = w1.z + w2.z, s3 = w1.w + w2.w;
        s0 = s0 > 0.f ? s0 : 0.2f * s0;
        s1 = s1 > 0.f ? s1 : 0.2f * s1;
        s2 = s2 > 0.f ? s2 : 0.2f * s2;
        s3 = s3 > 0.f ? s3 : 0.2f * s3;
        wSt[rr][0][k] = expf(s0) - 1.f;
        wSt[rr][1][k] = expf(s1) - 1.f;
        wSt[rr][2][k] = expf(s2) - 1.f;
        wSt[rr][3][k] = expf(s3) - 1.f;
    }
    __syncthreads();

    float a[16] = {};
    float wsum = 0.f;
    const unsigned char* hb = h_f8 + h * 256 + f * 16;
#pragma unroll 2
    for (int k = 0; k < deg; ++k) {
        float w = wSt[rr][h][k];
        uint4 v = *(const uint4*)(hb + (size_t)colsS[rr][k] * 1024);
        wsum += w;
        a[0]  += w * __builtin_amdgcn_cvt_f32_fp8(v.x, 0);
        a[1]  += w * __builtin_amdgcn_cvt_f32_fp8(v.x, 1);
        a[2]  += w * __builtin_amdgcn_cvt_f32_fp8(v.x, 2);
        a[3]  += w * __builtin_amdgcn_cvt_f32_fp8(v.x, 3);
        a[4]  += w * __builtin_amdgcn_cvt_f32_fp8(v.y, 0);
        a[5]  += w * __builtin_amdgcn_cvt_f32_fp8(v.y, 1);
        a[6]  += w * __builtin_amdgcn_cvt_f32_fp8(v.y, 2);
        a[7]  += w * __builtin_amdgcn_cvt_f32_fp8(v.y, 3);
        a[8]  += w * __builtin_amdgcn_cvt_f32_fp8(v.z, 0);
        a[9]  += w * __builtin_amdgcn_cvt_f32_fp8(v.z, 1);
        a[10] += w * __builtin_amdgcn_cvt_f32_fp8(v.z, 2);
        a[11] += w * __builtin_amdgcn_cvt_f32_fp8(v.z, 3);
        a[12] += w * __builtin_amdgcn_cvt_f32_fp8(v.w, 0);
        a[13] += w * __builtin_amdgcn_cvt_f32_fp8(v.w, 1);
        a[14] += w * __builtin_amdgcn_cvt_f32_fp8(v.w, 2);
        a[15] += w * __builtin_amdgcn_cvt_f32_fp8(v.w, 3);
    }
    float inv = 1.f / ((float)NNODES + wsum);
    float sq = 0.f;
    const float* cs = colsum + h * 256 + f * 16;
#pragma unroll
    for (int j = 0; j < 16; ++j) {
        float v = (cs[j] + a[j]) * inv;
        v = v > 0.f ? v : 0.2f * v;
        a[j] = v;
        sq += v * v;
    }
#pragma unroll
    for (int o = 1; o < 16; o <<= 1) sq += __shfl_xor(sq, o);   // 16-lane group = one head
    float rinv = 1.f / fmaxf(sqrtf(sq), 1e-12f);
    const float* bb = bias + h * 256 + f * 16;
#pragma unroll
    for (int j = 0; j < 16; ++j) {
        a[j] = a[j] * rinv + bb[j];
        // head-mean: sum over the 4 head-lanes (xor bits 4,5), same f
        a[j] += __shfl_xor(a[j], 16);
        a[j] += __shfl_xor(a[j], 32);
    }
    // lane (h,f) writes quarter h of feature-block f: elements f*16 + h*4 .. +3
    int off = i * 256 + f * 16 + h * 4;
    float4 pv = *(const float4*)(prev + off);
    float pvv[4] = {pv.x, pv.y, pv.z, pv.w};
    f32x4 ov; us4 ob;
#pragma unroll
    for (int j = 0; j < 4; ++j) {
        float o = a[h * 4 + j] * 0.25f + pvv[j];
        o = o > 0.f ? o : (expf(o) - 1.f);
        ov[j] = o;
        ob[j] = f2bf(o);
    }
    *(f32x4*)(outp + off) = ov;
    *(us4*)(out_bf + off) = ob;
}

extern "C" void kernel_launch(void* const* d_in, const int* in_sizes, int n_in,
                              void* d_out, int out_size, void* d_ws, size_t ws_size,
                              hipStream_t stream)
{
    const float* x  = (const float*)d_in[0];
    const int*   ei = (const int*)d_in[1];
    const float* W1 = (const float*)d_in[2];
    const float* a1 = (const float*)d_in[3];
    const float* b1 = (const float*)d_in[4];
    const float* Wk = (const float*)d_in[5];
    const float* ak = (const float*)d_in[6];
    const float* bk = (const float*)d_in[7];
    const float* pW = (const float*)d_in[8];
    const float* pb = (const float*)d_in[9];
    const int N = NNODES;
    const int E = in_sizes[1] / 2;
    const int* er = ei;
    const int* ec = ei + E;

    const size_t WHSZ = (size_t)2 * NHEADS * N + 1024;   // wh1 | wh2 | colsum per layer

    float* ws = (float*)d_ws;
    size_t off = 0;
    float* bufA    = ws + off; off += (size_t)N * 256;
    float* bufProj = ws + off; off += (size_t)N * 256;
    // --- single contiguous zero region: cnt | bitmap | whall ---
    size_t zoff = off;
    int*   cnt     = (int*)(ws + off); off += N;
    unsigned int* bitmap = (unsigned int*)(ws + off); off += (size_t)N * N / 32;
    float* whall   = ws + off; off += 4 * WHSZ;
    size_t zbytes = (off - zoff) * sizeof(float);
    // --- end zero region ---
    int*   cols    = (int*)(ws + off); off += (size_t)N * MAXDEG;
    unsigned char* h_f8 = (unsigned char*)(ws + off); off += (size_t)N * 1024 / 4;
    unsigned short* xb    = (unsigned short*)(ws + off); off += (size_t)N * 512 / 2;
    unsigned short* bufAb = (unsigned short*)(ws + off); off += (size_t)N * 256 / 2;
    unsigned short* Wt1   = (unsigned short*)(ws + off); off += (size_t)4 * 256 * 512 / 2;
    unsigned short* Wtk   = (unsigned short*)(ws + off); off += (size_t)12 * 256 * 256 / 2;
    unsigned short* pWt   = (unsigned short*)(ws + off); off += (size_t)256 * 512 / 2;

    (void)hipMemsetAsync(ws + zoff, 0, zbytes, stream);  // cnt + bitmap + all wh/colsum
    preamble<<<3968, 256, 0, stream>>>(er, ec, bitmap, cnt, cols, E,
                                       x, xb, W1, Wt1, pW, pWt, Wk, Wtk);

    for (int l = 0; l < 4; ++l) {
        int K = (l == 0) ? 512 : 256;
        const unsigned short* Wt = (l == 0) ? Wt1 : Wtk + (size_t)(l - 1) * 4 * 256 * 256;
        const float* av = (l == 0) ? a1 : ak + (size_t)(l - 1) * NHEADS * 512;
        const float* bv = (l == 0) ? b1 : bk + (size_t)(l - 1) * NHEADS * 256;
        const unsigned short* Ab = (l == 0) ? xb : bufAb;

        float* wh1    = whall + (size_t)l * WHSZ;        // [node][4]
        float* wh2    = wh1 + NHEADS * N;                // [node][4]
        float* colsum = wh2 + NHEADS * N;

        if (l == 0)
            gemm_mfma<1><<<1280, 256, 0, stream>>>(
                Ab, Wt, pWt, pb, bufProj, h_f8, av, wh1, wh2, colsum, K);
        else
            gemm_mfma<0><<<1024, 256, 0, stream>>>(
                Ab, Wt, nullptr, nullptr, nullptr, h_f8, av, wh1, wh2, colsum, K);

        const float* prev = (l == 0) ? bufProj : bufA;
        float* outp = (l == 3) ? (float*)d_out : bufA;
        row_attn<<<N / 4, 256, 0, stream>>>(h_f8, wh1, wh2, colsum, cnt, cols, bv, prev, outp, bufAb, N);
    }
}

// Round 18
// 174.765 us; speedup vs baseline: 1.4564x; 1.4564x over previous
//
#include <hip/hip_runtime.h>
#include <hip/hip_bf16.h>
#include <math.h>

#define NNODES 4096
#define NHEADS 4
#define MAXDEG 128

typedef __attribute__((ext_vector_type(8))) short  bf16x8;
typedef __attribute__((ext_vector_type(4))) float  f32x4;
typedef __attribute__((ext_vector_type(4))) unsigned short us4;

__device__ __forceinline__ unsigned short f2bf(float v) {
    unsigned int x = __float_as_uint(v);
    unsigned int r = (x + 0x7fffu + ((x >> 16) & 1u)) >> 16;   // RNE
    return (unsigned short)r;
}

// float -> fp8 e4m3fn (OCP), RNE. Software encode (cold path) consistent with
// gfx950's hardware OCP decode.
__device__ __forceinline__ unsigned char f2f8(float v) {
    unsigned int u = __float_as_uint(v);
    unsigned int s = (u >> 24) & 0x80u;
    u &= 0x7fffffffu;
    int e = (int)(u >> 23) - 127;
    if (e < -6) {                                   // fp8-subnormal: step 2^-9
        float q = __uint_as_float(u) * 512.f;
        int m = (int)rintf(q);
        if (m <= 0) return (unsigned char)s;
        if (m >= 8) return (unsigned char)(s | 0x08);
        return (unsigned char)(s | m);
    }
    unsigned int rr = (u + 0x7ffffu + ((u >> 20) & 1u)) >> 20;  // [exp8|man3]
    int e2 = (int)(rr >> 3) - 127;
    unsigned int m3 = rr & 7u;
    if (e2 > 8 || (e2 == 8 && m3 == 7u)) return (unsigned char)(s | 0x7e);  // clamp 448
    return (unsigned char)(s | (unsigned int)((e2 + 7) << 3) | m3);
}

__device__ __forceinline__ void gload_lds16(const unsigned short* g, unsigned short* l) {
    __builtin_amdgcn_global_load_lds(
        (const __attribute__((address_space(1))) unsigned int*)(g),
        (__attribute__((address_space(3))) unsigned int*)(l), 16, 0, 0);
}

// ---------------- fused preamble: csr | cvt | transposes, by blockIdx range ----------
__global__ __launch_bounds__(256) void preamble(
    const int* __restrict__ er, const int* __restrict__ ec,
    unsigned int* __restrict__ bitmap, int* __restrict__ cnt, int* __restrict__ cols, int E,
    const float* __restrict__ x, unsigned short* __restrict__ xb,
    const float* __restrict__ W1, unsigned short* __restrict__ Wt1,
    const float* __restrict__ pW, unsigned short* __restrict__ pWt,
    const float* __restrict__ Wk, unsigned short* __restrict__ Wtk)
{
    __shared__ float tile[32][33];
    int b = blockIdx.x;
    int tid = threadIdx.x;
    if (b < 512) {                                   // ---- CSR with bitmap dedupe
        int e = b * 256 + tid;
        if (e >= E) return;
        int r = er[e], c = ec[e];
        unsigned int idx = ((unsigned int)r << 12) | (unsigned int)c;
        unsigned int bit = 1u << (idx & 31);
        unsigned int old = atomicOr(&bitmap[idx >> 5], bit);
        if (!(old & bit)) {
            int slot = atomicAdd(&cnt[r], 1);
            if (slot < MAXDEG) cols[r * MAXDEG + slot] = c;
        }
    } else if (b < 2560) {                           // ---- fp32 -> bf16 (x)
        int i = (b - 512) * 256 + tid;
        float4 v = *(const float4*)(x + (size_t)i * 4);
        us4 o; o.x = f2bf(v.x); o.y = f2bf(v.y); o.z = f2bf(v.z); o.w = f2bf(v.w);
        *(us4*)(xb + (size_t)i * 4) = o;
    } else if (b < 3200) {                           // ---- K=512 transpose (W1 heads + pW)
        int idx = b - 2560;
        int k0 = (idx & 15) * 32;
        int j0 = ((idx >> 4) & 7) * 32;
        int z  = idx >> 7;                           // 0..4
        const float* W = (z < 4) ? W1 + (size_t)z * 512 * 256 : pW;
        unsigned short* Wt = (z < 4) ? Wt1 + (size_t)z * 256 * 512 : pWt;
        int tj = tid & 31, tk = tid >> 5;
#pragma unroll
        for (int it = 0; it < 4; ++it) {
            int kl = tk + it * 8;
            tile[kl][tj] = W[(size_t)(k0 + kl) * 256 + j0 + tj];
        }
        __syncthreads();
#pragma unroll
        for (int it = 0; it < 4; ++it) {
            int jl = tk + it * 8;
            Wt[(size_t)(j0 + jl) * 512 + k0 + tj] = f2bf(tile[tj][jl]);
        }
    } else {                                         // ---- K=256 transpose (Wk, 12 mats)
        int idx = b - 3200;
        int k0 = (idx & 7) * 32;
        int j0 = ((idx >> 3) & 7) * 32;
        int z  = idx >> 6;                           // 0..11
        const float* W = Wk + (size_t)z * 256 * 256;
        unsigned short* Wt = Wtk + (size_t)z * 256 * 256;
        int tj = tid & 31, tk = tid >> 5;
#pragma unroll
        for (int it = 0; it < 4; ++it) {
            int kl = tk + it * 8;
            tile[kl][tj] = W[(size_t)(k0 + kl) * 256 + j0 + tj];
        }
        __syncthreads();
#pragma unroll
        for (int it = 0; it < 4; ++it) {
            int jl = tk + it * 8;
            Wt[(size_t)(j0 + jl) * 256 + k0 + tj] = f2bf(tile[tj][jl]);
        }
    }
}

// ---------------- bf16 MFMA GEMM, 64x64 tile, BK=128, XCD-swizzled (R14 champion) ------
// wh1/wh2 epilogue atomics: HEAD-MAJOR (heads in separate cache lines; [node][4]
// layout caused cross-XCD atomic line ping-pong, +38us/dispatch — R17 lesson).
template <int HASPROJ>
__global__ __launch_bounds__(256) void gemm_mfma(
    const unsigned short* __restrict__ A, const unsigned short* __restrict__ Bt,
    const unsigned short* __restrict__ pBt, const float* __restrict__ pb,
    float* __restrict__ Cproj, unsigned char* __restrict__ Cf8,
    const float* __restrict__ av, float* __restrict__ wh1, float* __restrict__ wh2,
    float* __restrict__ colsum, int K)
{
    __shared__ unsigned short As[64 * 128];   // 64 rows x 256B = 16KB
    __shared__ unsigned short Bs[64 * 128];
    int tid = threadIdx.x;
    int lane = tid & 63;
    int wave = tid >> 6;
    int wr = wave >> 1, wc = wave & 1;

    // XCD-aware swizzle (bijective: gridDim.x % 8 == 0)
    const int WB = HASPROJ ? 20 : 16;         // bn count
    int nwg = gridDim.x;
    int orig = blockIdx.x;
    int swz = (orig & 7) * (nwg >> 3) + (orig >> 3);
    int bn = swz % WB;
    int bm = swz / WB;

    int tileM = bm * 64;
    bool isProj = HASPROJ && (bn >= 16);
    const unsigned short* B = isProj ? pBt + (size_t)(bn - 16) * 64 * K
                                     : Bt + (size_t)bn * 64 * K;

    f32x4 acc[2][2];
#pragma unroll
    for (int m = 0; m < 2; ++m)
#pragma unroll
        for (int n = 0; n < 2; ++n) acc[m][n] = (f32x4){0.f, 0.f, 0.f, 0.f};

    int rowr  = tid >> 4;                    // 0..15
    int gslot = (tid & 15) ^ (rowr & 7);
    const unsigned short* gA = A + (size_t)(tileM + rowr) * K + gslot * 8;
    const unsigned short* gB = B + (size_t)rowr * K + gslot * 8;
    unsigned short* lA = As + tid * 8;
    unsigned short* lB = Bs + tid * 8;

    int fr = lane & 15;
    int kq = lane >> 4;
    int nsteps = K >> 7;

    int arow[2], brow[2];
#pragma unroll
    for (int m = 0; m < 2; ++m) arow[m] = wr * 32 + m * 16 + fr;
#pragma unroll
    for (int n = 0; n < 2; ++n) brow[n] = wc * 32 + n * 16 + fr;

    for (int t = 0; t < nsteps; ++t) {
#pragma unroll
        for (int r = 0; r < 4; ++r) {
            gload_lds16(gA + (size_t)r * 16 * K, lA + r * 2048);
            gload_lds16(gB + (size_t)r * 16 * K, lB + r * 2048);
        }
        gA += 128; gB += 128;
        __syncthreads();
#pragma unroll
        for (int ks = 0; ks < 4; ++ks) {
            bf16x8 af[2], bfv[2];
#pragma unroll
            for (int m = 0; m < 2; ++m) {
                int sl = ((ks * 4 + kq) ^ (arow[m] & 7)) * 8;
                af[m] = *(const bf16x8*)(As + arow[m] * 128 + sl);
            }
#pragma unroll
            for (int n = 0; n < 2; ++n) {
                int sl = ((ks * 4 + kq) ^ (brow[n] & 7)) * 8;
                bfv[n] = *(const bf16x8*)(Bs + brow[n] * 128 + sl);
            }
#pragma unroll
            for (int m = 0; m < 2; ++m)
#pragma unroll
                for (int n = 0; n < 2; ++n)
                    acc[m][n] = __builtin_amdgcn_mfma_f32_16x16x32_bf16(
                        af[m], bfv[n], acc[m][n], 0, 0, 0);
        }
        if (t + 1 < nsteps) __syncthreads();
    }

    int crow0 = tileM + wr * 32;

    if (!isProj) {
        int ccol0 = bn * 64 + wc * 32;
        int head = bn >> 2;
#pragma unroll
        for (int n = 0; n < 2; ++n) {
            float s = 0.f;
#pragma unroll
            for (int m = 0; m < 2; ++m)
#pragma unroll
                for (int q = 0; q < 4; ++q) s += acc[m][n][q];
            s += __shfl_xor(s, 16);
            s += __shfl_xor(s, 32);
            if (kq == 0)
                atomicAdd(colsum + ccol0 + n * 16 + fr, s);
        }
        float c1[2], c2[2];
#pragma unroll
        for (int n = 0; n < 2; ++n) {
            int j = (ccol0 + n * 16 + fr) & 255;
            c1[n] = av[head * 512 + j];
            c2[n] = av[head * 512 + 256 + j];
        }
#pragma unroll
        for (int m = 0; m < 2; ++m)
#pragma unroll
            for (int q = 0; q < 4; ++q) {
                float p1 = 0.f, p2 = 0.f;
#pragma unroll
                for (int n = 0; n < 2; ++n) {
                    p1 += acc[m][n][q] * c1[n];
                    p2 += acc[m][n][q] * c2[n];
                }
#pragma unroll
                for (int o = 1; o < 16; o <<= 1) {
                    p1 += __shfl_xor(p1, o);
                    p2 += __shfl_xor(p2, o);
                }
                if (fr == 0) {
                    int r = crow0 + m * 16 + kq * 4 + q;
                    atomicAdd(wh1 + head * NNODES + r, p1);   // head-major
                    atomicAdd(wh2 + head * NNODES + r, p2);
                }
            }
        // fp8 C store, node-major (row stride 1024 bytes)
#pragma unroll
        for (int m = 0; m < 2; ++m)
#pragma unroll
            for (int n = 0; n < 2; ++n) {
                int r0 = crow0 + m * 16 + kq * 4;
                int c  = ccol0 + n * 16 + fr;
#pragma unroll
                for (int q = 0; q < 4; ++q)
                    Cf8[(size_t)(r0 + q) * 1024 + c] = f2f8(acc[m][n][q]);
            }
    } else {
        int pcol0 = (bn - 16) * 64 + wc * 32;
#pragma unroll
        for (int m = 0; m < 2; ++m)
#pragma unroll
            for (int n = 0; n < 2; ++n) {
                int r0 = crow0 + m * 16 + kq * 4;
                int c  = pcol0 + n * 16 + fr;
                float bv = pb[c & 255];
#pragma unroll
                for (int q = 0; q < 4; ++q)
                    Cproj[(size_t)(r0 + q) * 256 + c] = acc[m][n][q] + bv;
            }
    }
}

// ---------------- per-row attention: 4 rows/block, wave/row, fp8 uint4 gather ------
// lane = h*16 + f. Head-major wh (scalar loads); head-mean via shfl_xor; no fsum LDS.
__global__ __launch_bounds__(256) void row_attn(
    const unsigned char* __restrict__ h_f8, const float* __restrict__ wh1,
    const float* __restrict__ wh2, const float* __restrict__ colsum,
    const int* __restrict__ cnt, const int* __restrict__ cols,
    const float* __restrict__ bias, const float* __restrict__ prev,
    float* __restrict__ outp, unsigned short* __restrict__ out_bf, int N)
{
    int t = threadIdx.x;
    int rr = t >> 6;               // row-in-block 0..3
    int lane = t & 63;
    int h = lane >> 4;             // head
    int f = lane & 15;             // 16-feature slice
    int i = blockIdx.x * 4 + rr;
    __shared__ int   colsS[4][MAXDEG];
    __shared__ float wSt[4][4][MAXDEG];
    int deg = cnt[i];
    if (deg > MAXDEG) deg = MAXDEG;

    float w10 = wh1[0 * N + i], w11 = wh1[1 * N + i];
    float w12 = wh1[2 * N + i], w13 = wh1[3 * N + i];
    for (int k = lane; k < deg; k += 64) {
        int c = cols[i * MAXDEG + k];
        colsS[rr][k] = c;
        float s0 = w10 + wh2[0 * N + c];
        float s1 = w11 + wh2[1 * N + c];
        float s2 = w12 + wh2[2 * N + c];
        float s3 = w13 + wh2[3 * N + c];
        s0 = s0 > 0.f ? s0 : 0.2f * s0;
        s1 = s1 > 0.f ? s1 : 0.2f * s1;
        s2 = s2 > 0.f ? s2 : 0.2f * s2;
        s3 = s3 > 0.f ? s3 : 0.2f * s3;
        wSt[rr][0][k] = expf(s0) - 1.f;
        wSt[rr][1][k] = expf(s1) - 1.f;
        wSt[rr][2][k] = expf(s2) - 1.f;
        wSt[rr][3][k] = expf(s3) - 1.f;
    }
    __syncthreads();

    float a[16] = {};
    float wsum = 0.f;
    const unsigned char* hb = h_f8 + h * 256 + f * 16;
#pragma unroll 2
    for (int k = 0; k < deg; ++k) {
        float w = wSt[rr][h][k];
        uint4 v = *(const uint4*)(hb + (size_t)colsS[rr][k] * 1024);
        wsum += w;
        a[0]  += w * __builtin_amdgcn_cvt_f32_fp8(v.x, 0);
        a[1]  += w * __builtin_amdgcn_cvt_f32_fp8(v.x, 1);
        a[2]  += w * __builtin_amdgcn_cvt_f32_fp8(v.x, 2);
        a[3]  += w * __builtin_amdgcn_cvt_f32_fp8(v.x, 3);
        a[4]  += w * __builtin_amdgcn_cvt_f32_fp8(v.y, 0);
        a[5]  += w * __builtin_amdgcn_cvt_f32_fp8(v.y, 1);
        a[6]  += w * __builtin_amdgcn_cvt_f32_fp8(v.y, 2);
        a[7]  += w * __builtin_amdgcn_cvt_f32_fp8(v.y, 3);
        a[8]  += w * __builtin_amdgcn_cvt_f32_fp8(v.z, 0);
        a[9]  += w * __builtin_amdgcn_cvt_f32_fp8(v.z, 1);
        a[10] += w * __builtin_amdgcn_cvt_f32_fp8(v.z, 2);
        a[11] += w * __builtin_amdgcn_cvt_f32_fp8(v.z, 3);
        a[12] += w * __builtin_amdgcn_cvt_f32_fp8(v.w, 0);
        a[13] += w * __builtin_amdgcn_cvt_f32_fp8(v.w, 1);
        a[14] += w * __builtin_amdgcn_cvt_f32_fp8(v.w, 2);
        a[15] += w * __builtin_amdgcn_cvt_f32_fp8(v.w, 3);
    }
    float inv = 1.f / ((float)NNODES + wsum);
    float sq = 0.f;
    const float* cs = colsum + h * 256 + f * 16;
#pragma unroll
    for (int j = 0; j < 16; ++j) {
        float v = (cs[j] + a[j]) * inv;
        v = v > 0.f ? v : 0.2f * v;
        a[j] = v;
        sq += v * v;
    }
#pragma unroll
    for (int o = 1; o < 16; o <<= 1) sq += __shfl_xor(sq, o);   // 16-lane group = one head
    float rinv = 1.f / fmaxf(sqrtf(sq), 1e-12f);
    const float* bb = bias + h * 256 + f * 16;
#pragma unroll
    for (int j = 0; j < 16; ++j) {
        a[j] = a[j] * rinv + bb[j];
        // head-mean: sum over the 4 head-lanes (xor bits 4,5), same f
        a[j] += __shfl_xor(a[j], 16);
        a[j] += __shfl_xor(a[j], 32);
    }
    // lane (h,f) writes quarter h of feature-block f: elements f*16 + h*4 .. +3
    int off = i * 256 + f * 16 + h * 4;
    float4 pv = *(const float4*)(prev + off);
    float pvv[4] = {pv.x, pv.y, pv.z, pv.w};
    f32x4 ov; us4 ob;
#pragma unroll
    for (int j = 0; j < 4; ++j) {
        float o = a[h * 4 + j] * 0.25f + pvv[j];
        o = o > 0.f ? o : (expf(o) - 1.f);
        ov[j] = o;
        ob[j] = f2bf(o);
    }
    *(f32x4*)(outp + off) = ov;
    *(us4*)(out_bf + off) = ob;
}

extern "C" void kernel_launch(void* const* d_in, const int* in_sizes, int n_in,
                              void* d_out, int out_size, void* d_ws, size_t ws_size,
                              hipStream_t stream)
{
    const float* x  = (const float*)d_in[0];
    const int*   ei = (const int*)d_in[1];
    const float* W1 = (const float*)d_in[2];
    const float* a1 = (const float*)d_in[3];
    const float* b1 = (const float*)d_in[4];
    const float* Wk = (const float*)d_in[5];
    const float* ak = (const float*)d_in[6];
    const float* bk = (const float*)d_in[7];
    const float* pW = (const float*)d_in[8];
    const float* pb = (const float*)d_in[9];
    const int N = NNODES;
    const int E = in_sizes[1] / 2;
    const int* er = ei;
    const int* ec = ei + E;

    const size_t WHSZ = (size_t)2 * NHEADS * N + 1024;   // wh1 | wh2 | colsum per layer

    float* ws = (float*)d_ws;
    size_t off = 0;
    float* bufA    = ws + off; off += (size_t)N * 256;
    float* bufProj = ws + off; off += (size_t)N * 256;
    // --- single contiguous zero region: cnt | bitmap | whall ---
    size_t zoff = off;
    int*   cnt     = (int*)(ws + off); off += N;
    unsigned int* bitmap = (unsigned int*)(ws + off); off += (size_t)N * N / 32;
    float* whall   = ws + off; off += 4 * WHSZ;
    size_t zbytes = (off - zoff) * sizeof(float);
    // --- end zero region ---
    int*   cols    = (int*)(ws + off); off += (size_t)N * MAXDEG;
    unsigned char* h_f8 = (unsigned char*)(ws + off); off += (size_t)N * 1024 / 4;
    unsigned short* xb    = (unsigned short*)(ws + off); off += (size_t)N * 512 / 2;
    unsigned short* bufAb = (unsigned short*)(ws + off); off += (size_t)N * 256 / 2;
    unsigned short* Wt1   = (unsigned short*)(ws + off); off += (size_t)4 * 256 * 512 / 2;
    unsigned short* Wtk   = (unsigned short*)(ws + off); off += (size_t)12 * 256 * 256 / 2;
    unsigned short* pWt   = (unsigned short*)(ws + off); off += (size_t)256 * 512 / 2;

    (void)hipMemsetAsync(ws + zoff, 0, zbytes, stream);  // cnt + bitmap + all wh/colsum
    preamble<<<3968, 256, 0, stream>>>(er, ec, bitmap, cnt, cols, E,
                                       x, xb, W1, Wt1, pW, pWt, Wk, Wtk);

    for (int l = 0; l < 4; ++l) {
        int K = (l == 0) ? 512 : 256;
        const unsigned short* Wt = (l == 0) ? Wt1 : Wtk + (size_t)(l - 1) * 4 * 256 * 256;
        const float* av = (l == 0) ? a1 : ak + (size_t)(l - 1) * NHEADS * 512;
        const float* bv = (l == 0) ? b1 : bk + (size_t)(l - 1) * NHEADS * 256;
        const unsigned short* Ab = (l == 0) ? xb : bufAb;

        float* wh1    = whall + (size_t)l * WHSZ;        // head-major [4][N]
        float* wh2    = wh1 + NHEADS * N;                // head-major [4][N]
        float* colsum = wh2 + NHEADS * N;

        if (l == 0)
            gemm_mfma<1><<<1280, 256, 0, stream>>>(
                Ab, Wt, pWt, pb, bufProj, h_f8, av, wh1, wh2, colsum, K);
        else
            gemm_mfma<0><<<1024, 256, 0, stream>>>(
                Ab, Wt, nullptr, nullptr, nullptr, h_f8, av, wh1, wh2, colsum, K);

        const float* prev = (l == 0) ? bufProj : bufA;
        float* outp = (l == 3) ? (float*)d_out : bufA;
        row_attn<<<N / 4, 256, 0, stream>>>(h_f8, wh1, wh2, colsum, cnt, cols, bv, prev, outp, bufAb, N);
    }
}

// Round 20
// 172.558 us; speedup vs baseline: 1.4750x; 1.0128x over previous
//
#include <hip/hip_runtime.h>
#include <hip/hip_bf16.h>
#include <math.h>

#define NNODES 4096
#define NHEADS 4
#define MAXDEG 128

typedef __attribute__((ext_vector_type(8))) short  bf16x8;
typedef __attribute__((ext_vector_type(4))) float  f32x4;
typedef __attribute__((ext_vector_type(4))) unsigned short us4;

__device__ __forceinline__ unsigned short f2bf(float v) {
    unsigned int x = __float_as_uint(v);
    unsigned int r = (x + 0x7fffu + ((x >> 16) & 1u)) >> 16;   // RNE
    return (unsigned short)r;
}

// float -> fp8 e4m3fn (OCP), RNE. Software encode (cold path) consistent with
// gfx950's hardware OCP decode.
__device__ __forceinline__ unsigned char f2f8(float v) {
    unsigned int u = __float_as_uint(v);
    unsigned int s = (u >> 24) & 0x80u;
    u &= 0x7fffffffu;
    int e = (int)(u >> 23) - 127;
    if (e < -6) {                                   // fp8-subnormal: step 2^-9
        float q = __uint_as_float(u) * 512.f;
        int m = (int)rintf(q);
        if (m <= 0) return (unsigned char)s;
        if (m >= 8) return (unsigned char)(s | 0x08);
        return (unsigned char)(s | m);
    }
    unsigned int rr = (u + 0x7ffffu + ((u >> 20) & 1u)) >> 20;  // [exp8|man3]
    int e2 = (int)(rr >> 3) - 127;
    unsigned int m3 = rr & 7u;
    if (e2 > 8 || (e2 == 8 && m3 == 7u)) return (unsigned char)(s | 0x7e);  // clamp 448
    return (unsigned char)(s | (unsigned int)((e2 + 7) << 3) | m3);
}

__device__ __forceinline__ void gload_lds16(const unsigned short* g, unsigned short* l) {
    __builtin_amdgcn_global_load_lds(
        (const __attribute__((address_space(1))) unsigned int*)(g),
        (__attribute__((address_space(3))) unsigned int*)(l), 16, 0, 0);
}

// ---------------- fused preamble: csr | cvt | transposes, by blockIdx range ----------
__global__ __launch_bounds__(256) void preamble(
    const int* __restrict__ er, const int* __restrict__ ec,
    unsigned int* __restrict__ bitmap, int* __restrict__ cnt, int* __restrict__ cols, int E,
    const float* __restrict__ x, unsigned short* __restrict__ xb,
    const float* __restrict__ W1, unsigned short* __restrict__ Wt1,
    const float* __restrict__ pW, unsigned short* __restrict__ pWt,
    const float* __restrict__ Wk, unsigned short* __restrict__ Wtk)
{
    __shared__ float tile[32][33];
    int b = blockIdx.x;
    int tid = threadIdx.x;
    if (b < 512) {                                   // ---- CSR with bitmap dedupe
        int e = b * 256 + tid;
        if (e >= E) return;
        int r = er[e], c = ec[e];
        unsigned int idx = ((unsigned int)r << 12) | (unsigned int)c;
        unsigned int bit = 1u << (idx & 31);
        unsigned int old = atomicOr(&bitmap[idx >> 5], bit);
        if (!(old & bit)) {
            int slot = atomicAdd(&cnt[r], 1);
            if (slot < MAXDEG) cols[r * MAXDEG + slot] = c;
        }
    } else if (b < 2560) {                           // ---- fp32 -> bf16 (x)
        int i = (b - 512) * 256 + tid;
        float4 v = *(const float4*)(x + (size_t)i * 4);
        us4 o; o.x = f2bf(v.x); o.y = f2bf(v.y); o.z = f2bf(v.z); o.w = f2bf(v.w);
        *(us4*)(xb + (size_t)i * 4) = o;
    } else if (b < 3200) {                           // ---- K=512 transpose (W1 heads + pW)
        int idx = b - 2560;
        int k0 = (idx & 15) * 32;
        int j0 = ((idx >> 4) & 7) * 32;
        int z  = idx >> 7;                           // 0..4
        const float* W = (z < 4) ? W1 + (size_t)z * 512 * 256 : pW;
        unsigned short* Wt = (z < 4) ? Wt1 + (size_t)z * 256 * 512 : pWt;
        int tj = tid & 31, tk = tid >> 5;
#pragma unroll
        for (int it = 0; it < 4; ++it) {
            int kl = tk + it * 8;
            tile[kl][tj] = W[(size_t)(k0 + kl) * 256 + j0 + tj];
        }
        __syncthreads();
#pragma unroll
        for (int it = 0; it < 4; ++it) {
            int jl = tk + it * 8;
            Wt[(size_t)(j0 + jl) * 512 + k0 + tj] = f2bf(tile[tj][jl]);
        }
    } else {                                         // ---- K=256 transpose (Wk, 12 mats)
        int idx = b - 3200;
        int k0 = (idx & 7) * 32;
        int j0 = ((idx >> 3) & 7) * 32;
        int z  = idx >> 6;                           // 0..11
        const float* W = Wk + (size_t)z * 256 * 256;
        unsigned short* Wt = Wtk + (size_t)z * 256 * 256;
        int tj = tid & 31, tk = tid >> 5;
#pragma unroll
        for (int it = 0; it < 4; ++it) {
            int kl = tk + it * 8;
            tile[kl][tj] = W[(size_t)(k0 + kl) * 256 + j0 + tj];
        }
        __syncthreads();
#pragma unroll
        for (int it = 0; it < 4; ++it) {
            int jl = tk + it * 8;
            Wt[(size_t)(j0 + jl) * 256 + k0 + tj] = f2bf(tile[tj][jl]);
        }
    }
}

// ---------------- bf16 MFMA GEMM, 64x64 tile, BK=128, XCD-swizzled (champion) ------
template <int HASPROJ>
__global__ __launch_bounds__(256) void gemm_mfma(
    const unsigned short* __restrict__ A, const unsigned short* __restrict__ Bt,
    const unsigned short* __restrict__ pBt, const float* __restrict__ pb,
    float* __restrict__ Cproj, unsigned char* __restrict__ Cf8,
    const float* __restrict__ av, float* __restrict__ wh1, float* __restrict__ wh2,
    float* __restrict__ colsum, int K)
{
    __shared__ unsigned short As[64 * 128];   // 64 rows x 256B = 16KB
    __shared__ unsigned short Bs[64 * 128];
    int tid = threadIdx.x;
    int lane = tid & 63;
    int wave = tid >> 6;
    int wr = wave >> 1, wc = wave & 1;

    // XCD-aware swizzle (bijective: gridDim.x % 8 == 0)
    const int WB = HASPROJ ? 20 : 16;         // bn count
    int nwg = gridDim.x;
    int orig = blockIdx.x;
    int swz = (orig & 7) * (nwg >> 3) + (orig >> 3);
    int bn = swz % WB;
    int bm = swz / WB;

    int tileM = bm * 64;
    bool isProj = HASPROJ && (bn >= 16);
    const unsigned short* B = isProj ? pBt + (size_t)(bn - 16) * 64 * K
                                     : Bt + (size_t)bn * 64 * K;

    f32x4 acc[2][2];
#pragma unroll
    for (int m = 0; m < 2; ++m)
#pragma unroll
        for (int n = 0; n < 2; ++n) acc[m][n] = (f32x4){0.f, 0.f, 0.f, 0.f};

    int rowr  = tid >> 4;                    // 0..15
    int gslot = (tid & 15) ^ (rowr & 7);
    const unsigned short* gA = A + (size_t)(tileM + rowr) * K + gslot * 8;
    const unsigned short* gB = B + (size_t)rowr * K + gslot * 8;
    unsigned short* lA = As + tid * 8;
    unsigned short* lB = Bs + tid * 8;

    int fr = lane & 15;
    int kq = lane >> 4;
    int nsteps = K >> 7;

    int arow[2], brow[2];
#pragma unroll
    for (int m = 0; m < 2; ++m) arow[m] = wr * 32 + m * 16 + fr;
#pragma unroll
    for (int n = 0; n < 2; ++n) brow[n] = wc * 32 + n * 16 + fr;

    for (int t = 0; t < nsteps; ++t) {
#pragma unroll
        for (int r = 0; r < 4; ++r) {
            gload_lds16(gA + (size_t)r * 16 * K, lA + r * 2048);
            gload_lds16(gB + (size_t)r * 16 * K, lB + r * 2048);
        }
        gA += 128; gB += 128;
        __syncthreads();
#pragma unroll
        for (int ks = 0; ks < 4; ++ks) {
            bf16x8 af[2], bfv[2];
#pragma unroll
            for (int m = 0; m < 2; ++m) {
                int sl = ((ks * 4 + kq) ^ (arow[m] & 7)) * 8;
                af[m] = *(const bf16x8*)(As + arow[m] * 128 + sl);
            }
#pragma unroll
            for (int n = 0; n < 2; ++n) {
                int sl = ((ks * 4 + kq) ^ (brow[n] & 7)) * 8;
                bfv[n] = *(const bf16x8*)(Bs + brow[n] * 128 + sl);
            }
#pragma unroll
            for (int m = 0; m < 2; ++m)
#pragma unroll
                for (int n = 0; n < 2; ++n)
                    acc[m][n] = __builtin_amdgcn_mfma_f32_16x16x32_bf16(
                        af[m], bfv[n], acc[m][n], 0, 0, 0);
        }
        if (t + 1 < nsteps) __syncthreads();
    }

    int crow0 = tileM + wr * 32;

    if (!isProj) {
        int ccol0 = bn * 64 + wc * 32;
        int head = bn >> 2;
#pragma unroll
        for (int n = 0; n < 2; ++n) {
            float s = 0.f;
#pragma unroll
            for (int m = 0; m < 2; ++m)
#pragma unroll
                for (int q = 0; q < 4; ++q) s += acc[m][n][q];
            s += __shfl_xor(s, 16);
            s += __shfl_xor(s, 32);
            if (kq == 0)
                atomicAdd(colsum + ccol0 + n * 16 + fr, s);
        }
        float c1[2], c2[2];
#pragma unroll
        for (int n = 0; n < 2; ++n) {
            int j = (ccol0 + n * 16 + fr) & 255;
            c1[n] = av[head * 512 + j];
            c2[n] = av[head * 512 + 256 + j];
        }
#pragma unroll
        for (int m = 0; m < 2; ++m)
#pragma unroll
            for (int q = 0; q < 4; ++q) {
                float p1 = 0.f, p2 = 0.f;
#pragma unroll
                for (int n = 0; n < 2; ++n) {
                    p1 += acc[m][n][q] * c1[n];
                    p2 += acc[m][n][q] * c2[n];
                }
#pragma unroll
                for (int o = 1; o < 16; o <<= 1) {
                    p1 += __shfl_xor(p1, o);
                    p2 += __shfl_xor(p2, o);
                }
                if (fr == 0) {
                    int r = crow0 + m * 16 + kq * 4 + q;
                    atomicAdd(wh1 + head * NNODES + r, p1);   // head-major (R17 lesson)
                    atomicAdd(wh2 + head * NNODES + r, p2);
                }
            }
        // fp8 C store, node-major (row stride 1024 bytes)
#pragma unroll
        for (int m = 0; m < 2; ++m)
#pragma unroll
            for (int n = 0; n < 2; ++n) {
                int r0 = crow0 + m * 16 + kq * 4;
                int c  = ccol0 + n * 16 + fr;
#pragma unroll
                for (int q = 0; q < 4; ++q)
                    Cf8[(size_t)(r0 + q) * 1024 + c] = f2f8(acc[m][n][q]);
            }
    } else {
        int pcol0 = (bn - 16) * 64 + wc * 32;
#pragma unroll
        for (int m = 0; m < 2; ++m)
#pragma unroll
            for (int n = 0; n < 2; ++n) {
                int r0 = crow0 + m * 16 + kq * 4;
                int c  = pcol0 + n * 16 + fr;
                float bv = pb[c & 255];
#pragma unroll
                for (int q = 0; q < 4; ++q)
                    Cproj[(size_t)(r0 + q) * 256 + c] = acc[m][n][q] + bv;
            }
    }
}

// ---------------- per-row attention: 4 rows/block, 64 thr/row, fp8 uint4 gather ------
__global__ __launch_bounds__(256) void row_attn(
    const unsigned char* __restrict__ h_f8, const float* __restrict__ wh1,
    const float* __restrict__ wh2, const float* __restrict__ colsum,
    const int* __restrict__ cnt, const int* __restrict__ cols,
    const float* __restrict__ bias, const float* __restrict__ prev,
    float* __restrict__ outp, unsigned short* __restrict__ out_bf, int N)
{
    int t = threadIdx.x;
    int rr = t >> 6;               // row-in-block 0..3
    int lane = t & 63;
    int h = lane >> 4;             // head
    int f = lane & 15;             // 16-feature slice
    int i = blockIdx.x * 4 + rr;
    __shared__ int   colsS[4][MAXDEG];
    __shared__ float wSt[4][4][MAXDEG];
    __shared__ float fsum[4][1024];
    int deg = cnt[i];
    if (deg > MAXDEG) deg = MAXDEG;

    float w10 = wh1[0 * N + i], w11 = wh1[1 * N + i];
    float w12 = wh1[2 * N + i], w13 = wh1[3 * N + i];
    for (int k = lane; k < deg; k += 64) {
        int c = cols[i * MAXDEG + k];
        colsS[rr][k] = c;
        float s0 = w10 + wh2[0 * N + c];
        float s1 = w11 + wh2[1 * N + c];
        float s2 = w12 + wh2[2 * N + c];
        float s3 = w13 + wh2[3 * N + c];
        s0 = s0 > 0.f ? s0 : 0.2f * s0;
        s1 = s1 > 0.f ? s1 : 0.2f * s1;
        s2 = s2 > 0.f ? s2 : 0.2f * s2;
        s3 = s3 > 0.f ? s3 : 0.2f * s3;
        wSt[rr][0][k] = expf(s0) - 1.f;
        wSt[rr][1][k] = expf(s1) - 1.f;
        wSt[rr][2][k] = expf(s2) - 1.f;
        wSt[rr][3][k] = expf(s3) - 1.f;
    }
    __syncthreads();

    float a[16] = {};
    float wsum = 0.f;
    const unsigned char* hb = h_f8 + h * 256 + f * 16;
#pragma unroll 2
    for (int k = 0; k < deg; ++k) {
        float w = wSt[rr][h][k];
        uint4 v = *(const uint4*)(hb + (size_t)colsS[rr][k] * 1024);
        wsum += w;
        a[0]  += w * __builtin_amdgcn_cvt_f32_fp8(v.x, 0);
        a[1]  += w * __builtin_amdgcn_cvt_f32_fp8(v.x, 1);
        a[2]  += w * __builtin_amdgcn_cvt_f32_fp8(v.x, 2);
        a[3]  += w * __builtin_amdgcn_cvt_f32_fp8(v.x, 3);
        a[4]  += w * __builtin_amdgcn_cvt_f32_fp8(v.y, 0);
        a[5]  += w * __builtin_amdgcn_cvt_f32_fp8(v.y, 1);
        a[6]  += w * __builtin_amdgcn_cvt_f32_fp8(v.y, 2);
        a[7]  += w * __builtin_amdgcn_cvt_f32_fp8(v.y, 3);
        a[8]  += w * __builtin_amdgcn_cvt_f32_fp8(v.z, 0);
        a[9]  += w * __builtin_amdgcn_cvt_f32_fp8(v.z, 1);
        a[10] += w * __builtin_amdgcn_cvt_f32_fp8(v.z, 2);
        a[11] += w * __builtin_amdgcn_cvt_f32_fp8(v.z, 3);
        a[12] += w * __builtin_amdgcn_cvt_f32_fp8(v.w, 0);
        a[13] += w * __builtin_amdgcn_cvt_f32_fp8(v.w, 1);
        a[14] += w * __builtin_amdgcn_cvt_f32_fp8(v.w, 2);
        a[15] += w * __builtin_amdgcn_cvt_f32_fp8(v.w, 3);
    }
    float inv = 1.f / ((float)NNODES + wsum);
    float sq = 0.f;
    const float* cs = colsum + h * 256 + f * 16;
#pragma unroll
    for (int j = 0; j < 16; ++j) {
        float v = (cs[j] + a[j]) * inv;
        v = v > 0.f ? v : 0.2f * v;
        a[j] = v;
        sq += v * v;
    }
#pragma unroll
    for (int o = 1; o < 16; o <<= 1) sq += __shfl_xor(sq, o);   // 16-lane group = one head
    float rinv = 1.f / fmaxf(sqrtf(sq), 1e-12f);
    const float* bb = bias + h * 256 + f * 16;
    float* fs = &fsum[rr][h * 256 + f * 16];
#pragma unroll
    for (int jq = 0; jq < 4; ++jq) {
        f32x4 ov;
#pragma unroll
        for (int j = 0; j < 4; ++j) ov[j] = a[jq * 4 + j] * rinv + bb[jq * 4 + j];
        *(f32x4*)(fs + jq * 4) = ov;
    }
    __syncthreads();

#pragma unroll
    for (int r2 = 0; r2 < 4; ++r2) {
        int ii = blockIdx.x * 4 + r2;
        float o = (fsum[r2][t] + fsum[r2][256 + t] + fsum[r2][512 + t] + fsum[r2][768 + t]) * 0.25f
                  + prev[(size_t)ii * 256 + t];
        o = o > 0.f ? o : (expf(o) - 1.f);
        outp[(size_t)ii * 256 + t] = o;
        out_bf[(size_t)ii * 256 + t] = f2bf(o);
    }
}

extern "C" void kernel_launch(void* const* d_in, const int* in_sizes, int n_in,
                              void* d_out, int out_size, void* d_ws, size_t ws_size,
                              hipStream_t stream)
{
    const float* x  = (const float*)d_in[0];
    const int*   ei = (const int*)d_in[1];
    const float* W1 = (const float*)d_in[2];
    const float* a1 = (const float*)d_in[3];
    const float* b1 = (const float*)d_in[4];
    const float* Wk = (const float*)d_in[5];
    const float* ak = (const float*)d_in[6];
    const float* bk = (const float*)d_in[7];
    const float* pW = (const float*)d_in[8];
    const float* pb = (const float*)d_in[9];
    const int N = NNODES;
    const int E = in_sizes[1] / 2;
    const int* er = ei;
    const int* ec = ei + E;

    const size_t WHSZ = (size_t)2 * NHEADS * N + 1024;   // wh1 | wh2 | colsum per layer

    float* ws = (float*)d_ws;
    size_t off = 0;
    float* bufA    = ws + off; off += (size_t)N * 256;
    float* bufProj = ws + off; off += (size_t)N * 256;
    // --- single contiguous zero region: cnt | bitmap | whall ---
    size_t zoff = off;
    int*   cnt     = (int*)(ws + off); off += N;
    unsigned int* bitmap = (unsigned int*)(ws + off); off += (size_t)N * N / 32;
    float* whall   = ws + off; off += 4 * WHSZ;
    size_t zbytes = (off - zoff) * sizeof(float);
    // --- end zero region ---
    int*   cols    = (int*)(ws + off); off += (size_t)N * MAXDEG;
    unsigned char* h_f8 = (unsigned char*)(ws + off); off += (size_t)N * 1024 / 4;
    unsigned short* xb    = (unsigned short*)(ws + off); off += (size_t)N * 512 / 2;
    unsigned short* bufAb = (unsigned short*)(ws + off); off += (size_t)N * 256 / 2;
    unsigned short* Wt1   = (unsigned short*)(ws + off); off += (size_t)4 * 256 * 512 / 2;
    unsigned short* Wtk   = (unsigned short*)(ws + off); off += (size_t)12 * 256 * 256 / 2;
    unsigned short* pWt   = (unsigned short*)(ws + off); off += (size_t)256 * 512 / 2;

    (void)hipMemsetAsync(ws + zoff, 0, zbytes, stream);  // cnt + bitmap + all wh/colsum
    preamble<<<3968, 256, 0, stream>>>(er, ec, bitmap, cnt, cols, E,
                                       x, xb, W1, Wt1, pW, pWt, Wk, Wtk);

    for (int l = 0; l < 4; ++l) {
        int K = (l == 0) ? 512 : 256;
        const unsigned short* Wt = (l == 0) ? Wt1 : Wtk + (size_t)(l - 1) * 4 * 256 * 256;
        const float* av = (l == 0) ? a1 : ak + (size_t)(l - 1) * NHEADS * 512;
        const float* bv = (l == 0) ? b1 : bk + (size_t)(l - 1) * NHEADS * 256;
        const unsigned short* Ab = (l == 0) ? xb : bufAb;

        float* wh1    = whall + (size_t)l * WHSZ;        // head-major [4][N]
        float* wh2    = wh1 + NHEADS * N;                // head-major [4][N]
        float* colsum = wh2 + NHEADS * N;

        if (l == 0)
            gemm_mfma<1><<<1280, 256, 0, stream>>>(
                Ab, Wt, pWt, pb, bufProj, h_f8, av, wh1, wh2, colsum, K);
        else
            gemm_mfma<0><<<1024, 256, 0, stream>>>(
                Ab, Wt, nullptr, nullptr, nullptr, h_f8, av, wh1, wh2, colsum, K);

        const float* prev = (l == 0) ? bufProj : bufA;
        float* outp = (l == 3) ? (float*)d_out : bufA;
        row_attn<<<N / 4, 256, 0, stream>>>(h_f8, wh1, wh2, colsum, cnt, cols, bv, prev, outp, bufAb, N);
    }
}